// Round 11
// baseline (654.854 us; speedup 1.0000x reference)
//
#include <hip/hip_runtime.h>
#include <hip/hip_bf16.h>
#include <stdint.h>

#define IN_F 4096
#define OUT_F 4096

typedef __attribute__((ext_vector_type(8))) __bf16 bf16x8;
typedef __attribute__((ext_vector_type(4))) float f32x4;

__device__ __forceinline__ void gl_lds_16(const void* g, void* l) {
    __builtin_amdgcn_global_load_lds((const __attribute__((address_space(1))) void*)g,
                                     (__attribute__((address_space(3))) void*)l,
                                     16, 0, 0);
}

// ---- sorted-COO scatter into zeroed W (run owner sums fp32, stores bf16) ----
// memset+scatter is the verified-best W build (R4/R9 search builds both lost).
__global__ void scatter_w(const float* __restrict__ vals, const int* __restrict__ idx,
                          __bf16* __restrict__ W, int nnz) {
    int i = blockIdx.x * blockDim.x + threadIdx.x;
    if (i >= nnz) return;
    const int id = idx[i];
    if (i > 0 && idx[i - 1] == id) return;
    float s = vals[i];
    for (int j = i + 1; j < nnz && idx[j] == id; ++j) s += vals[j];
    W[id] = (__bf16)s;
}

// ---- GEMM: C[M,N] = x[M,K](fp32) * W[N,K]^T + bias,  fp32-A converted in-kernel ----
// R11: the standalone cvt pass (x fp32 -> Xb bf16, 192MB) is ELIMINATED; the GEMM
// reads x directly and converts during A-staging:
//   A-loads(tau) issue at tau-3 (named float4 set, x2 rotation — no runtime reg
//   indexing), cvt+ds_write at tau-2 into buf tau&3, barrier, frag-read tau-1,
//   MFMA tau. B keeps global_load_lds (unchanged).
// Hazards: A-region WAR is 2 barriers upstream; ds_write visibility via
// lgkmcnt(0) before each barrier (raw s_barrier does NOT drain); float4 reg deps
// are compiler-inserted vmcnt waits (issued a full tile earlier -> free).
// vmcnt ledger (order-insensitive): exactly 6 VMEM/tile (4 A + 2 B) -> end-of-tile
// vmcnt(6) keeps this tile's ops and drains all prior => certifies B-stage(t+2)
// for next tile's frag reads regardless of intra-tile VMEM order. Prologue/tail
// use vmcnt(0) (one-time conservative drains).
// Everything else is the verified R10 structure: 256x256, BK=32, 8 waves 2Mx4N,
// quad-buffered LDS, chunk-XOR swizzle (conflicts=0), reg-double-buffered frags,
// SGB interleave, hoisted end-wait, no setprio in loop (R6), no wave-role
// branches (R8 scratch catastrophe), no sched_barrier(0) (R5).
#define BM 256
#define BN 256
#define BK 32
#define NT (IN_F / BK)   // 128 K-tiles

__global__ __launch_bounds__(512, 2) void gemm_bf16_bt(
    const float* __restrict__ X, const __bf16* __restrict__ B,
    const float* __restrict__ bias, float* __restrict__ C,
    int M, int N, int K)
{
    __shared__ __align__(128) __bf16 lds[4][16384];

    const int t512 = threadIdx.x;          // 0..511
    const int wave = t512 >> 6;            // 0..7
    const int lane = t512 & 63;
    const int wm = wave >> 2;              // 0..1  (M half)
    const int wn = wave & 3;               // 0..3  (N quarter)
    const int lq = lane >> 4;              // 0..3
    const int lr = lane & 15;              // 0..15

    // XCD swizzle: grid is exactly 512 = 8 XCDs x 64 contiguous slots
    const int bid  = blockIdx.x;
    const int wgid = (bid & 7) * 64 + (bid >> 3);
    const int mt = wgid >> 4;              // 0..31
    const int nt = wgid & 15;              // 0..15
    const int tileM = mt * BM;
    const int tileN = nt * BN;

    // staging geometry: thread u covers row u>>2, 16B-bf16 chunk; LDS dest linear
    // (u*16B), global SOURCE chunk is the swizzle-inverse permutation.
    const int srow = t512 >> 2;            // 0..127
    const int scol = ((t512 & 3) ^ ((t512 >> 3) & 3)) * 8;   // element col

    const float*  gx0 = X + (size_t)(tileM + srow) * K + scol;        // A half0 fp32
    const float*  gx1 = X + (size_t)(tileM + 128 + srow) * K + scol;  // A half1 fp32
    const __bf16* gB0 = B + (size_t)(tileN + srow) * K + scol;
    const __bf16* gB1 = B + (size_t)(tileN + 128 + srow) * K + scol;

#define STAGE_B(buf, k0) do { \
        gl_lds_16(gB0 + (k0), &lds[buf][8192]         + t512 * 8); \
        gl_lds_16(gB1 + (k0), &lds[buf][8192 + 4096]  + t512 * 8); } while (0)

// A path: load 32B fp32 per half into a named float4 set (4 VMEM total)
#define LOADA(R, k0) do { \
        R##a = *(const float4*)(gx0 + (k0)); \
        R##b = *(const float4*)(gx0 + (k0) + 4); \
        R##c = *(const float4*)(gx1 + (k0)); \
        R##d = *(const float4*)(gx1 + (k0) + 4); } while (0)

// convert + 2x ds_write_b128 into buf wb's A-region (linear dest = u*16B)
#define WRITEA(R, wb) do { \
        bf16x8 w0_, w1_; \
        w0_[0]=(__bf16)R##a.x; w0_[1]=(__bf16)R##a.y; w0_[2]=(__bf16)R##a.z; w0_[3]=(__bf16)R##a.w; \
        w0_[4]=(__bf16)R##b.x; w0_[5]=(__bf16)R##b.y; w0_[6]=(__bf16)R##b.z; w0_[7]=(__bf16)R##b.w; \
        w1_[0]=(__bf16)R##c.x; w1_[1]=(__bf16)R##c.y; w1_[2]=(__bf16)R##c.z; w1_[3]=(__bf16)R##c.w; \
        w1_[4]=(__bf16)R##d.x; w1_[5]=(__bf16)R##d.y; w1_[6]=(__bf16)R##d.z; w1_[7]=(__bf16)R##d.w; \
        *(bf16x8*)(&lds[wb][0]    + t512 * 8) = w0_; \
        *(bf16x8*)(&lds[wb][4096] + t512 * 8) = w1_; } while (0)

    // fragment read offsets with matching XOR (row bases are multiples of 16):
    const int cswz = (lq ^ ((lr >> 1) & 3)) * 8;
    const int aoff = (wm * 128 + lr) * BK + cswz;            // fa[mi] at +mi*512
    const int boff = 8192 + (wn * 64 + lr) * BK + cswz;      // fb[ni] at +ni*512

    f32x4 acc[8][4] = {};
    bf16x8 fa0[8], fb0[4], fa1[8], fb1[4];
    float4 r0a, r0b, r0c, r0d, r1a, r1b, r1c, r1d;

#define MM2(FAc, FBc, MI0, MI1) do {                                            \
        _Pragma("unroll") for (int ni_ = 0; ni_ < 4; ++ni_)                     \
            acc[MI0][ni_] = __builtin_amdgcn_mfma_f32_16x16x32_bf16(            \
                FAc[MI0], FBc[ni_], acc[MI0][ni_], 0, 0, 0);                    \
        _Pragma("unroll") for (int ni_ = 0; ni_ < 4; ++ni_)                     \
            acc[MI1][ni_] = __builtin_amdgcn_mfma_f32_16x16x32_bf16(            \
                FAc[MI1], FBc[ni_], acc[MI1][ni_], 0, 0, 0);                    \
    } while (0)

// main-loop tile: Rl = float4 set to load A(t+3) into; Rw = set holding A(t+2).
#define TILE_MAIN(T, FAc, FBc, FAn, FBn, Rl, Rw) do {                           \
        const int t_ = (T);                                                     \
        const int pk_ = (t_ + 3) * BK;                                          \
        const int pb_ = (t_ + 3) & 3;                                           \
        const int wb_ = (t_ + 2) & 3;                                           \
        const __bf16* nb_ = &lds[(t_ + 1) & 3][0];                              \
        LOADA(Rl, pk_);                 /* 4 VMEM */                            \
        STAGE_B(pb_, pk_);              /* 2 VMEM */                            \
        WRITEA(Rw, wb_);                /* cvt VALU + 2 DS_WRITE */             \
        FAn[0] = *(const bf16x8*)&nb_[aoff];                                    \
        FAn[1] = *(const bf16x8*)&nb_[aoff + 512];                              \
        FBn[0] = *(const bf16x8*)&nb_[boff];                                    \
        MM2(FAc, FBc, 0, 1);                                                    \
        FBn[1] = *(const bf16x8*)&nb_[boff + 512];                              \
        FBn[2] = *(const bf16x8*)&nb_[boff + 1024];                             \
        FBn[3] = *(const bf16x8*)&nb_[boff + 1536];                             \
        MM2(FAc, FBc, 2, 3);                                                    \
        FAn[2] = *(const bf16x8*)&nb_[aoff + 1024];                             \
        FAn[3] = *(const bf16x8*)&nb_[aoff + 1536];                             \
        FAn[4] = *(const bf16x8*)&nb_[aoff + 2048];                             \
        MM2(FAc, FBc, 4, 5);                                                    \
        FAn[5] = *(const bf16x8*)&nb_[aoff + 2560];                             \
        FAn[6] = *(const bf16x8*)&nb_[aoff + 3072];                             \
        FAn[7] = *(const bf16x8*)&nb_[aoff + 3584];                             \
        __builtin_amdgcn_sched_group_barrier(0x030, 4, 0); /* 4 VMEM (A) */     \
        __builtin_amdgcn_sched_group_barrier(0x030, 2, 0); /* 2 VMEM (B) */     \
        __builtin_amdgcn_sched_group_barrier(0x200, 2, 0); /* 2 DS_WRITE */     \
        __builtin_amdgcn_sched_group_barrier(0x100, 3, 0); /* 3 DS_READ  */     \
        __builtin_amdgcn_sched_group_barrier(0x008, 8, 0); /* 8 MFMA     */     \
        __builtin_amdgcn_sched_group_barrier(0x100, 3, 0);                      \
        __builtin_amdgcn_sched_group_barrier(0x008, 8, 0);                      \
        __builtin_amdgcn_sched_group_barrier(0x100, 3, 0);                      \
        __builtin_amdgcn_sched_group_barrier(0x008, 8, 0);                      \
        __builtin_amdgcn_sched_group_barrier(0x100, 3, 0);                      \
        /* hoisted end-wait: exactly this tile's 6 VMEM stay in flight;         \
           drains tile t-1's -> certifies B-stage(t+2) for next tile's reads */ \
        asm volatile("s_waitcnt vmcnt(6)" ::: "memory");                        \
        MM2(FAc, FBc, 6, 7);                                                    \
        __builtin_amdgcn_sched_group_barrier(0x008, 8, 0);                      \
        asm volatile("s_waitcnt lgkmcnt(0)" ::: "memory");                      \
        __builtin_amdgcn_s_barrier();                                           \
        asm volatile("" ::: "memory");                                          \
    } while (0)

// tail tile: literal T -> guards fold; conservative vmcnt(0).
#define TILE_TAIL(T, FAc, FBc, FAn, FBn, Rl, Rw) do {                           \
        const int t_ = (T);                                                     \
        if (t_ + 3 < NT) { LOADA(Rl, (t_ + 3) * BK); STAGE_B((t_ + 3) & 3, (t_ + 3) * BK); } \
        if (t_ + 2 < NT) { WRITEA(Rw, (t_ + 2) & 3); }                          \
        if (t_ + 1 < NT) {                                                      \
            const __bf16* nb_ = &lds[(t_ + 1) & 3][0];                          \
            _Pragma("unroll") for (int mi = 0; mi < 8; ++mi)                    \
                FAn[mi] = *(const bf16x8*)&nb_[aoff + mi * 512];                \
            _Pragma("unroll") for (int ni = 0; ni < 4; ++ni)                    \
                FBn[ni] = *(const bf16x8*)&nb_[boff + ni * 512];                \
        }                                                                       \
        _Pragma("unroll") for (int mi = 0; mi < 8; ++mi)                        \
            _Pragma("unroll") for (int ni = 0; ni < 4; ++ni)                    \
                acc[mi][ni] = __builtin_amdgcn_mfma_f32_16x16x32_bf16(          \
                    FAc[mi], FBc[ni], acc[mi][ni], 0, 0, 0);                    \
        asm volatile("s_waitcnt vmcnt(0)" ::: "memory");                        \
        asm volatile("s_waitcnt lgkmcnt(0)" ::: "memory");                      \
        if (t_ < NT - 1) {                                                      \
            __builtin_amdgcn_s_barrier();                                       \
            asm volatile("" ::: "memory");                                      \
        }                                                                       \
    } while (0)

    // ---- prologue: A(0),A(1) -> regs; B(0,1,2) -> LDS DMA; write A(0),A(1);
    //      reload A(2); conservative full drain; barrier; frag-read(0). ----
    LOADA(r0, 0);            // A(0)
    LOADA(r1, 32);           // A(1)
    STAGE_B(0, 0); STAGE_B(1, 32); STAGE_B(2, 64);
    WRITEA(r0, 0);           // compiler waits on r0 loads
    WRITEA(r1, 1);
    LOADA(r0, 64);           // A(2) -> set r0 (free after write)
    asm volatile("s_waitcnt vmcnt(0)" ::: "memory");   // drain B(0..2)+A(2): one-time
    asm volatile("s_waitcnt lgkmcnt(0)" ::: "memory");
    __builtin_amdgcn_s_barrier();
    asm volatile("" ::: "memory");
    {
        const __bf16* nb_ = &lds[0][0];
#pragma unroll
        for (int mi = 0; mi < 8; ++mi) fa0[mi] = *(const bf16x8*)&nb_[aoff + mi * 512];
#pragma unroll
        for (int ni = 0; ni < 4; ++ni) fb0[ni] = *(const bf16x8*)&nb_[boff + ni * 512];
    }

    // main loop: tiles 0..123. Even: write r0 / load r1. Odd: write r1 / load r0.
    for (int t = 0; t < 124; t += 2) {
        TILE_MAIN(t,     fa0, fb0, fa1, fb1, r1, r0);
        TILE_MAIN(t + 1, fa1, fb1, fa0, fb0, r0, r1);
    }
    // tail: tiles 124..127 (literal folding; alternation continues)
    TILE_TAIL(124, fa0, fb0, fa1, fb1, r1, r0);
    TILE_TAIL(125, fa1, fb1, fa0, fb0, r0, r1);
    TILE_TAIL(126, fa0, fb0, fa1, fb1, r1, r0);
    TILE_TAIL(127, fa1, fb1, fa0, fb0, r0, r1);

    // ---- epilogue: C/D layout col=lane&15, row=(lane>>4)*4+reg  [m89-verified] ----
    float bv[4];
#pragma unroll
    for (int ni = 0; ni < 4; ++ni) bv[ni] = bias[tileN + wn * 64 + ni * 16 + lr];
#pragma unroll
    for (int mi = 0; mi < 8; ++mi) {
#pragma unroll
        for (int ni = 0; ni < 4; ++ni) {
            const int gn = tileN + wn * 64 + ni * 16 + lr;
#pragma unroll
            for (int r = 0; r < 4; ++r) {
                const int gm = tileM + wm * 128 + mi * 16 + lq * 4 + r;
                C[(size_t)gm * N + gn] = acc[mi][ni][r] + bv[ni];
            }
        }
    }
#undef TILE_TAIL
#undef TILE_MAIN
#undef MM2
#undef WRITEA
#undef LOADA
#undef STAGE_B
}

extern "C" void kernel_launch(void* const* d_in, const int* in_sizes, int n_in,
                              void* d_out, int out_size, void* d_ws, size_t ws_size,
                              hipStream_t stream) {
    const float* x    = (const float*)d_in[0];   // (4,2048,4096) fp32
    const float* vals = (const float*)d_in[1];   // (NNZ,) fp32
    const float* bias = (const float*)d_in[2];   // (4096,) fp32
    const int*   idx  = (const int*)d_in[3];     // (NNZ,) sorted flat indices
    float* out = (float*)d_out;                  // (4,2048,4096) fp32

    const int nnz = in_sizes[1];
    const int K = IN_F, N = OUT_F;
    const int M = in_sizes[0] / K;               // 8192

    // workspace: W bf16 only (Xb eliminated — GEMM reads x fp32 directly)
    __bf16* Wb = (__bf16*)d_ws;
    const int wElems = N * K;                    // 16777216
    const int scatBlocks = (nnz + 255) / 256;    // 6554

    hipMemsetAsync(Wb, 0, (size_t)wElems * sizeof(__bf16), stream);
    scatter_w<<<scatBlocks, 256, 0, stream>>>(vals, idx, Wb, nnz);

    gemm_bf16_bt<<<(M / BM) * (N / BN), 512, 0, stream>>>(x, Wb, bias, out, M, N, K);
}

// Round 12
// 441.694 us; speedup vs baseline: 1.4826x; 1.4826x over previous
//
#include <hip/hip_runtime.h>
#include <hip/hip_bf16.h>
#include <stdint.h>

#define IN_F 4096
#define OUT_F 4096

typedef __attribute__((ext_vector_type(8))) __bf16 bf16x8;
typedef __attribute__((ext_vector_type(4))) float f32x4;

__device__ __forceinline__ void gl_lds_16(const void* g, void* l) {
    __builtin_amdgcn_global_load_lds((const __attribute__((address_space(1))) void*)g,
                                     (__attribute__((address_space(3))) void*)l,
                                     16, 0, 0);
}

// ---- fused: sorted-COO scatter + x fp32->bf16 cvt ----
// R12: scatter blocks FIRST [0, scatBlocks) — they are latency-bound (random 2B
// stores) and previously launched after all 16384 cvt blocks, exposing their
// latency tail at the end of the dispatch. First = fully hidden under the
// BW-bound cvt. Code otherwise identical to the verified R10 pre-pass.
// Known dead ends (do not re-attempt): search-based W build (R4 block-level,
// R9 thread-level: both lost 40-50us to memset+scatter); split dispatches (R7:
// +9us); in-GEMM A-cvt (R11: GEMM 2.2x regression).
__global__ void cvt_and_scatter(const float* __restrict__ x, __bf16* __restrict__ Xb, int n8,
                                const float* __restrict__ vals, const int* __restrict__ idx,
                                __bf16* __restrict__ W, int nnz, int scatBlocks) {
    if ((int)blockIdx.x < scatBlocks) {
        // flat_idx sorted -> duplicate runs adjacent; run owner sums fp32, stores bf16.
        int i = blockIdx.x * blockDim.x + threadIdx.x;
        if (i >= nnz) return;
        const int id = idx[i];
        if (i > 0 && idx[i - 1] == id) return;
        float s = vals[i];
        for (int j = i + 1; j < nnz && idx[j] == id; ++j) s += vals[j];
        W[id] = (__bf16)s;
    } else {
        int i = (blockIdx.x - scatBlocks) * blockDim.x + threadIdx.x;
        if (i < n8) {
            const float4* src = (const float4*)(x + (size_t)i * 8);
            float4 v0 = src[0], v1 = src[1];
            bf16x8 o;
            o[0] = (__bf16)v0.x; o[1] = (__bf16)v0.y; o[2] = (__bf16)v0.z; o[3] = (__bf16)v0.w;
            o[4] = (__bf16)v1.x; o[5] = (__bf16)v1.y; o[6] = (__bf16)v1.z; o[7] = (__bf16)v1.w;
            *(bf16x8*)(Xb + (size_t)i * 8) = o;
        }
    }
}

// ---- GEMM: C[M,N] = A[M,K] * B[N,K]^T + bias,  bf16 in / fp32 out ----
// EXACT R10 GEMM (verified 214.5us / 1287 TF / MfmaUtil 59.0 / conflicts 0).
// 256x256 tile, BK=32, 8 waves (2Mx4N), quad-buffered LDS, prefetch distance 3,
// chunk-XOR swizzle, register-double-buffered fragments, SGB interleave,
// hoisted end-of-tile vmcnt(4).
// Hard boundaries established this session (do NOT re-attempt):
//   R5: sched_barrier(0) read-pinning -> LDS-queue backpressure, serial pipes.
//   R6: setprio inside loop -> splits SGB scheduling region, interleave dies.
//   R8: per-wave role if/else -> loop state spills to scratch (14x).
//   R11: in-GEMM fp32->bf16 A-staging (reg->ds_write) -> 2.2x regression.
#define BM 256
#define BN 256
#define BK 32
#define NT (IN_F / BK)   // 128 K-tiles

__global__ __launch_bounds__(512, 2) void gemm_bf16_bt(
    const __bf16* __restrict__ A, const __bf16* __restrict__ B,
    const float* __restrict__ bias, float* __restrict__ C,
    int M, int N, int K)
{
    __shared__ __align__(128) __bf16 lds[4][16384];

    const int t512 = threadIdx.x;          // 0..511
    const int wave = t512 >> 6;            // 0..7
    const int lane = t512 & 63;
    const int wm = wave >> 2;              // 0..1  (M half)
    const int wn = wave & 3;               // 0..3  (N quarter)
    const int lq = lane >> 4;              // 0..3
    const int lr = lane & 15;              // 0..15

    // XCD swizzle: grid is exactly 512 = 8 XCDs x 64 contiguous slots
    const int bid  = blockIdx.x;
    const int wgid = (bid & 7) * 64 + (bid >> 3);
    const int mt = wgid >> 4;              // 0..31
    const int nt = wgid & 15;              // 0..15
    const int tileM = mt * BM;
    const int tileN = nt * BN;

    // staging: thread u covers row u>>2; DEST chunk u&3 linear (global_load_lds),
    // SOURCE chunk swizzle-inverse: c = (u&3) ^ ((row>>1)&3) = (u&3) ^ ((u>>3)&3).
    const int srow = t512 >> 2;            // 0..127
    const int scol = ((t512 & 3) ^ ((t512 >> 3) & 3)) * 8;

    const __bf16* gA0 = A + (size_t)(tileM + srow) * K + scol;
    const __bf16* gA1 = A + (size_t)(tileM + 128 + srow) * K + scol;
    const __bf16* gB0 = B + (size_t)(tileN + srow) * K + scol;
    const __bf16* gB1 = B + (size_t)(tileN + 128 + srow) * K + scol;

#define STAGE_A(buf, k0) do { \
        gl_lds_16(gA0 + (k0), &lds[buf][0]    + t512 * 8); \
        gl_lds_16(gA1 + (k0), &lds[buf][4096] + t512 * 8); } while (0)
#define STAGE_B(buf, k0) do { \
        gl_lds_16(gB0 + (k0), &lds[buf][8192]         + t512 * 8); \
        gl_lds_16(gB1 + (k0), &lds[buf][8192 + 4096]  + t512 * 8); } while (0)

    // fragment read offsets with matching XOR (row bases are multiples of 16):
    const int cswz = (lq ^ ((lr >> 1) & 3)) * 8;
    const int aoff = (wm * 128 + lr) * BK + cswz;            // fa[mi] at +mi*512
    const int boff = 8192 + (wn * 64 + lr) * BK + cswz;      // fb[ni] at +ni*512

    f32x4 acc[8][4] = {};
    bf16x8 fa0[8], fb0[4], fa1[8], fb1[4];

#define MM2(FAc, FBc, MI0, MI1) do {                                            \
        _Pragma("unroll") for (int ni_ = 0; ni_ < 4; ++ni_)                     \
            acc[MI0][ni_] = __builtin_amdgcn_mfma_f32_16x16x32_bf16(            \
                FAc[MI0], FBc[ni_], acc[MI0][ni_], 0, 0, 0);                    \
        _Pragma("unroll") for (int ni_ = 0; ni_ < 4; ++ni_)                     \
            acc[MI1][ni_] = __builtin_amdgcn_mfma_f32_16x16x32_bf16(            \
                FAc[MI1], FBc[ni_], acc[MI1][ni_], 0, 0, 0);                    \
    } while (0)

// main-loop tile (tiles 0..123: always stage + always read-ahead), interleaved.
#define TILE_MAIN(T, FAc, FBc, FAn, FBn) do {                                   \
        const int t_ = (T);                                                     \
        const int pb_ = (t_ + 3) & 3; const int pk_ = (t_ + 3) * BK;            \
        const __bf16* nb_ = &lds[(t_ + 1) & 3][0];                              \
        /* ---- region 1: 4 VMEM, 12 DS, 24 MFMA ---- */                        \
        STAGE_A(pb_, pk_);                                                      \
        FAn[0] = *(const bf16x8*)&nb_[aoff];                                    \
        FAn[1] = *(const bf16x8*)&nb_[aoff + 512];                              \
        FBn[0] = *(const bf16x8*)&nb_[boff];                                    \
        MM2(FAc, FBc, 0, 1);                                                    \
        STAGE_B(pb_, pk_);                                                      \
        FBn[1] = *(const bf16x8*)&nb_[boff + 512];                              \
        FBn[2] = *(const bf16x8*)&nb_[boff + 1024];                             \
        FBn[3] = *(const bf16x8*)&nb_[boff + 1536];                             \
        MM2(FAc, FBc, 2, 3);                                                    \
        FAn[2] = *(const bf16x8*)&nb_[aoff + 1024];                             \
        FAn[3] = *(const bf16x8*)&nb_[aoff + 1536];                             \
        FAn[4] = *(const bf16x8*)&nb_[aoff + 2048];                             \
        MM2(FAc, FBc, 4, 5);                                                    \
        FAn[5] = *(const bf16x8*)&nb_[aoff + 2560];                             \
        FAn[6] = *(const bf16x8*)&nb_[aoff + 3072];                             \
        FAn[7] = *(const bf16x8*)&nb_[aoff + 3584];                             \
        __builtin_amdgcn_sched_group_barrier(0x030, 2, 0); /* 2 VMEM  */        \
        __builtin_amdgcn_sched_group_barrier(0x100, 3, 0); /* 3 DS_rd */        \
        __builtin_amdgcn_sched_group_barrier(0x008, 8, 0); /* 8 MFMA  */        \
        __builtin_amdgcn_sched_group_barrier(0x030, 2, 0);                      \
        __builtin_amdgcn_sched_group_barrier(0x100, 3, 0);                      \
        __builtin_amdgcn_sched_group_barrier(0x008, 8, 0);                      \
        __builtin_amdgcn_sched_group_barrier(0x100, 3, 0);                      \
        __builtin_amdgcn_sched_group_barrier(0x008, 8, 0);                      \
        __builtin_amdgcn_sched_group_barrier(0x100, 3, 0);                      \
        /* ---- hoisted wait: overlaps with final MFMA group ---- */            \
        asm volatile("s_waitcnt vmcnt(4)" ::: "memory");                        \
        /* ---- region 2: 8 MFMA (no VMEM -> certification intact) ---- */      \
        MM2(FAc, FBc, 6, 7);                                                    \
        __builtin_amdgcn_sched_group_barrier(0x008, 8, 0);                      \
        __builtin_amdgcn_s_barrier();                                           \
        asm volatile("" ::: "memory");                                          \
    } while (0)

// tail tile: literal T -> all conditionals fold at compile time.
#define TILE(T, FAc, FBc, FAn, FBn) do {                                        \
        const int t_ = (T);                                                     \
        if (t_ + 3 < NT) {                                                      \
            const int pb_ = (t_ + 3) & 3; const int pk_ = (t_ + 3) * BK;        \
            STAGE_A(pb_, pk_); STAGE_B(pb_, pk_);                               \
        }                                                                       \
        if (t_ + 1 < NT) {                                                      \
            const __bf16* nb_ = &lds[(t_ + 1) & 3][0];                          \
            _Pragma("unroll") for (int mi = 0; mi < 8; ++mi)                    \
                FAn[mi] = *(const bf16x8*)&nb_[aoff + mi * 512];                \
            _Pragma("unroll") for (int ni = 0; ni < 4; ++ni)                    \
                FBn[ni] = *(const bf16x8*)&nb_[boff + ni * 512];                \
        }                                                                       \
        _Pragma("unroll") for (int mi = 0; mi < 8; ++mi)                        \
            _Pragma("unroll") for (int ni = 0; ni < 4; ++ni)                    \
                acc[mi][ni] = __builtin_amdgcn_mfma_f32_16x16x32_bf16(          \
                    FAc[mi], FBc[ni], acc[mi][ni], 0, 0, 0);                    \
        if (t_ < NT - 3)       asm volatile("s_waitcnt vmcnt(4)" ::: "memory"); \
        else if (t_ == NT - 3) asm volatile("s_waitcnt vmcnt(0)" ::: "memory"); \
        if (t_ < NT - 1) {                                                      \
            __builtin_amdgcn_s_barrier();                                       \
            asm volatile("" ::: "memory");                                      \
        }                                                                       \
    } while (0)

    // ---- prologue: stage 0,1,2; certify stages 0+1 for ALL waves; frags(0) ----
    STAGE_A(0, 0);   STAGE_B(0, 0);
    STAGE_A(1, 32);  STAGE_B(1, 32);
    STAGE_A(2, 64);  STAGE_B(2, 64);
    asm volatile("s_waitcnt vmcnt(4)" ::: "memory");
    __builtin_amdgcn_s_barrier();
    asm volatile("" ::: "memory");
    {
        const __bf16* nb_ = &lds[0][0];
#pragma unroll
        for (int mi = 0; mi < 8; ++mi) fa0[mi] = *(const bf16x8*)&nb_[aoff + mi * 512];
#pragma unroll
        for (int ni = 0; ni < 4; ++ni) fb0[ni] = *(const bf16x8*)&nb_[boff + ni * 512];
    }

    // main loop: tiles 0..123 (t+3 <= 126 < NT and t+1 <= 124 < NT always)
    for (int t = 0; t < 124; t += 2) {
        TILE_MAIN(t,     fa0, fb0, fa1, fb1);
        TILE_MAIN(t + 1, fa1, fb1, fa0, fb0);
    }
    // tail: tiles 124..127, literal-folded conditionals
    TILE(124, fa0, fb0, fa1, fb1);
    TILE(125, fa1, fb1, fa0, fb0);
    TILE(126, fa0, fb0, fa1, fb1);
    TILE(127, fa1, fb1, fa0, fb0);

    // ---- epilogue: C/D layout col=lane&15, row=(lane>>4)*4+reg  [m89-verified] ----
    float bv[4];
#pragma unroll
    for (int ni = 0; ni < 4; ++ni) bv[ni] = bias[tileN + wn * 64 + ni * 16 + lr];
#pragma unroll
    for (int mi = 0; mi < 8; ++mi) {
#pragma unroll
        for (int ni = 0; ni < 4; ++ni) {
            const int gn = tileN + wn * 64 + ni * 16 + lr;
#pragma unroll
            for (int r = 0; r < 4; ++r) {
                const int gm = tileM + wm * 128 + mi * 16 + lq * 4 + r;
                C[(size_t)gm * N + gn] = acc[mi][ni][r] + bv[ni];
            }
        }
    }
#undef TILE
#undef TILE_MAIN
#undef MM2
#undef STAGE_A
#undef STAGE_B
}

extern "C" void kernel_launch(void* const* d_in, const int* in_sizes, int n_in,
                              void* d_out, int out_size, void* d_ws, size_t ws_size,
                              hipStream_t stream) {
    const float* x    = (const float*)d_in[0];   // (4,2048,4096) fp32
    const float* vals = (const float*)d_in[1];   // (NNZ,) fp32
    const float* bias = (const float*)d_in[2];   // (4096,) fp32
    const int*   idx  = (const int*)d_in[3];     // (NNZ,) sorted flat indices
    float* out = (float*)d_out;                  // (4,2048,4096) fp32

    const int nnz = in_sizes[1];
    const int K = IN_F, N = OUT_F;
    const int M = in_sizes[0] / K;               // 8192

    // workspace: [0,32M) W bf16 | [32M,96M) x bf16
    char* ws = (char*)d_ws;
    __bf16* Wb = (__bf16*)ws;
    __bf16* Xb = (__bf16*)(ws + (size_t)32 * 1024 * 1024);

    const int wElems = N * K;                    // 16777216
    const int xElems = M * K;                    // 33554432
    const int n8 = xElems / 8;                   // 4194304 cvt threads
    const int cvtBlocks = n8 / 256;              // 16384
    const int scatBlocks = (nnz + 255) / 256;    // 6554

    hipMemsetAsync(Wb, 0, (size_t)wElems * sizeof(__bf16), stream);
    // scatter blocks first: latency-bound random stores start immediately and
    // hide under the 16384 BW-bound cvt blocks (previously they trailed).
    cvt_and_scatter<<<scatBlocks + cvtBlocks, 256, 0, stream>>>(
        x, Xb, n8, vals, idx, Wb, nnz, scatBlocks);

    gemm_bf16_bt<<<(M / BM) * (N / BN), 512, 0, stream>>>(Xb, Wb, bias, out, M, N, K);
}